// Round 14
// baseline (118.714 us; speedup 1.0000x reference)
//
#include <hip/hip_runtime.h>

// Problem constants (match reference)
#define N_ITEMS   64
#define CAPACITY  102.0f
#define N_PGD     120
#define ETA       0.1f

typedef float v2f __attribute__((ext_vector_type(2)));

// ---- DPP helpers: butterfly reductions over 4-lane quads ------------------
//   0xB1 = quad_perm [1,0,3,2] -> lane ^ 1
//   0x4E = quad_perm [2,3,0,1] -> lane ^ 2
// Both are quad-local, so a 4-lane problem-group never leaks into neighbors.
// All 4 lanes end bitwise-identical after the butterfly, so per-group
// decisions (bracket updates, lam) are uniform within the group.
template <int CTRL>
__device__ __forceinline__ float dpp_movf(float x) {
  return __builtin_bit_cast(
      float, __builtin_amdgcn_update_dpp(0, __builtin_bit_cast(int, x), CTRL,
                                         0xF, 0xF, true));
}

__device__ __forceinline__ float grp4_sum(float x) {
  x += dpp_movf<0xB1>(x);
  x += dpp_movf<0x4E>(x);
  return x;
}

__device__ __forceinline__ float grp4_max(float x) {
  x = fmaxf(x, dpp_movf<0xB1>(x));
  x = fmaxf(x, dpp_movf<0x4E>(x));
  return x;
}

__device__ __forceinline__ float clip01(float z) {
  return __builtin_amdgcn_fmed3f(z, 0.0f, 1.0f);  // single v_med3_f32
}

// False-position estimate from the bracket. Invariant: flo > 0 >= fhi
// (Illinois halving scales f-values by 0.5, preserving signs), so
// fhi - flo < 0 strictly -> no divide-by-zero/NaN; the med3 clamp at the
// call site absorbs any rounding excursion outside [lo, hi].
__device__ __forceinline__ float false_pos(float lo, float flo, float hi,
                                           float fhi) {
  const float t = fhi * __builtin_amdgcn_rcpf(fhi - flo);
  return fmaf(-t, hi - lo, hi);  // hi - fhi*(hi-lo)/(fhi-flo)
}

// 4 lanes per row, 16 items per lane. 16384 rows -> 65536 threads
// (1024 waves = 1 wave/SIMD). R13 base; R14 replaces the serial eval1->eval2
// chain with two INDEPENDENT probes at lam_est +- delta (delta from the
// tracked lam drift) that the scheduler can overlap, plus a 4th Illinois
// eval whenever any group's probe pair fails to straddle its root.
__global__ __launch_bounds__(256, 1) void pgd_knapsack(
    const float* __restrict__ costs, const float* __restrict__ weights,
    float* __restrict__ out) {
  const int tid  = blockIdx.x * 256 + threadIdx.x;
  const int sub  = tid & 3;                 // lane within row-group
  const int base = (tid >> 2) * N_ITEMS + sub * 16;

  v2f w[8], ec[8], x[8], y[8];

  float B;     // bracket half-width: g(-B) = sum(w), g(+B) = 0 by construction
  float flo0;  // f(-B) = sum(w) - CAPACITY, exact, no eval needed
  {
    float cab = 0.0f;
#pragma unroll
    for (int u = 0; u < 4; ++u) {
      const float4 cq = *reinterpret_cast<const float4*>(costs + base + 4 * u);
      const float4 wq =
          *reinterpret_cast<const float4*>(weights + sub * 16 + 4 * u);
      w[2 * u]      = (v2f){wq.x, wq.y};
      w[2 * u + 1]  = (v2f){wq.z, wq.w};
      ec[2 * u]     = (v2f){ETA * cq.x, ETA * cq.y};
      ec[2 * u + 1] = (v2f){ETA * cq.z, ETA * cq.w};
      y[2 * u]      = (v2f){clip01(cq.x), clip01(cq.y)};
      y[2 * u + 1]  = (v2f){clip01(cq.z), clip01(cq.w)};
      cab = fmaxf(cab, fmaxf(fmaxf(fabsf(cq.x), fabsf(cq.y)),
                             fmaxf(fabsf(cq.z), fabsf(cq.w))));
    }
    cab = grp4_max(cab);
    // Every PGD iterate satisfies y_j in [-0.1 - eta*cab, 1 + eta*cab]
    // (since (1 - eta/||x||) * x_j in [-eta, 1]); with w_j >= 1 this makes
    // +-B a valid bracket: all coords clipped to 1 at -B, to 0 at +B.
    B = fmaf(ETA, cab, 1.1f) + 1e-3f;
    v2f sw = (w[0] + w[1]) + (w[2] + w[3]);
    sw = sw + ((w[4] + w[5]) + (w[6] + w[7]));
    flo0 = grp4_sum(sw.x + sw.y) - CAPACITY;  // = 340 - 102, exact
  }
  const float fhi0 = -CAPACITY;  // f(+B) = 0 - CAPACITY, exact

  float lam_est = 0.0f;  // unclamped root estimate, warm start across iters
  float drift   = 0.0f;  // |lam_t - lam_{t-1}|, sets the probe spread

  // g(lam) - CAPACITY over the 4-lane group (16 items/lane, 4 indep chains).
  auto eval_f = [&](float lam) -> float {
    const v2f nl = {-lam, -lam};
    v2f q[4];
#pragma unroll
    for (int p = 0; p < 4; ++p) {
      const v2f z0 = __builtin_elementwise_fma(nl, w[2 * p], y[2 * p]);
      const v2f z1 = __builtin_elementwise_fma(nl, w[2 * p + 1], y[2 * p + 1]);
      const v2f t0 = {clip01(z0.x), clip01(z0.y)};
      const v2f t1 = {clip01(z1.x), clip01(z1.y)};
      const v2f qq = w[2 * p] * t0;
      q[p] = __builtin_elementwise_fma(w[2 * p + 1], t1, qq);
    }
    const v2f qs = (q[0] + q[1]) + (q[2] + q[3]);
    return grp4_sum(qs.x + qs.y) - CAPACITY;
  };

  auto epilogue = [&](float pick) {
    drift   = fabsf(pick - lam_est);
    lam_est = pick;
    const float lam_use = fmaxf(pick, 0.0f);  // inactive constraint -> 0
    const v2f nl = {-lam_use, -lam_use};
#pragma unroll
    for (int p = 0; p < 8; ++p) {
      const v2f z = __builtin_elementwise_fma(nl, w[p], y[p]);
      x[p] = (v2f){clip01(z.x), clip01(z.y)};
    }
  };

  // ---- sequential solver (R13, bitwise): cold-start iterations -----------
  // warm probe + 2 Illinois false positions + exact final pick. 3 evals =
  // verified accuracy floor (R8); no data-dependent freeze (R6).
  auto solve_seq = [&]() {
    float lo = -B, hi = B, flo = flo0, fhi = fhi0;
    bool prevpos;
    float lam = lam_est;  // always inside [-B, B]
    {
      const float f = eval_f(lam);
      const bool pos = f > 0.0f;
      flo = pos ? f : flo;
      lo  = pos ? lam : lo;
      fhi = pos ? fhi : f;
      hi  = pos ? hi : lam;
      prevpos = pos;
    }
#pragma unroll
    for (int k = 0; k < 2; ++k) {
      lam = __builtin_amdgcn_fmed3f(false_pos(lo, flo, hi, fhi), lo, hi);
      const float fhi_a = prevpos ? 0.5f * fhi : fhi;  // off critical path
      const float flo_a = prevpos ? flo : 0.5f * flo;
      const float f = eval_f(lam);
      const bool pos = f > 0.0f;
      flo = pos ? f : flo_a;
      lo  = pos ? lam : lo;
      fhi = pos ? fhi_a : f;
      hi  = pos ? hi : lam;
      prevpos = pos;
    }
    epilogue(__builtin_amdgcn_fmed3f(false_pos(lo, flo, hi, fhi), lo, hi));
  };

  // ---- paired solver: warm iterations ------------------------------------
  // Probes at lam_est +- delta are INDEPENDENT (8 concurrent FMA chains, two
  // overlapping DPP reduces). Straddle -> 2-sided bracket of width 2*delta
  // (tighter than seq after 2 evals) -> eval3 secant is near-exact. If ANY
  // group misses (pair same-signed), run a 4th Illinois eval so miss-groups
  // still get 3 sequential-quality refinements (>= R13 accuracy everywhere).
  auto solve_pair = [&]() {
    const float delta = fmaf(2.0f, drift, 1e-4f);
    const float p1 = __builtin_amdgcn_fmed3f(lam_est - delta, -B, B);
    const float p2 = __builtin_amdgcn_fmed3f(lam_est + delta, -B, B);
    const float f1 = eval_f(p1);  // independent of f2 -> scheduler overlaps
    const float f2 = eval_f(p2);
    // monotone g: f1 >= f2 since p1 <= p2
    const bool pos1 = f1 > 0.0f;
    const bool pos2 = f2 > 0.0f;
    float lo  = pos2 ? p2 : (pos1 ? p1 : -B);
    float flo = pos2 ? f2 : (pos1 ? f1 : flo0);
    float hi  = !pos1 ? p1 : (!pos2 ? p2 : B);
    float fhi = !pos1 ? f1 : (!pos2 ? f2 : fhi0);
    const bool miss = (pos1 == pos2);  // pair failed to straddle the root

    // eval 3: false position (first sequential step; no halving yet)
    float lam = __builtin_amdgcn_fmed3f(false_pos(lo, flo, hi, fhi), lo, hi);
    bool prevpos;
    {
      const float f = eval_f(lam);
      const bool pos = f > 0.0f;
      flo = pos ? f : flo;
      lo  = pos ? lam : lo;
      fhi = pos ? fhi : f;
      hi  = pos ? hi : lam;
      prevpos = pos;
    }

    // eval 4: only when some group's pair missed (rare in steady state)
    if (__any(miss)) {
      lam = __builtin_amdgcn_fmed3f(false_pos(lo, flo, hi, fhi), lo, hi);
      const float fhi_a = prevpos ? 0.5f * fhi : fhi;
      const float flo_a = prevpos ? flo : 0.5f * flo;
      const float f = eval_f(lam);
      const bool pos = f > 0.0f;
      flo = pos ? f : flo_a;
      lo  = pos ? lam : lo;
      fhi = pos ? fhi_a : f;
      hi  = pos ? hi : lam;
    }

    epilogue(__builtin_amdgcn_fmed3f(false_pos(lo, flo, hi, fhi), lo, hi));
  };

  // y-update between projections: y = (1 - eta/||x||)*x + eta*c
  auto update_y = [&]() {
    v2f a = x[0] * x[0];
    a = __builtin_elementwise_fma(x[1], x[1], a);
    v2f b = x[2] * x[2];
    b = __builtin_elementwise_fma(x[3], x[3], b);
    v2f c2 = x[4] * x[4];
    c2 = __builtin_elementwise_fma(x[5], x[5], c2);
    v2f d = x[6] * x[6];
    d = __builtin_elementwise_fma(x[7], x[7], d);
    const v2f ab = (a + b) + (c2 + d);
    const float s2  = grp4_sum(ab.x + ab.y);
    const float inv = __builtin_amdgcn_rsqf(s2 + 1e-12f);
    const float s   = 1.0f - ETA * inv;
    const v2f sv = {s, s};
#pragma unroll
    for (int p = 0; p < 8; ++p)
      y[p] = __builtin_elementwise_fma(sv, x[p], ec[p]);
  };

  // Cold start: iterations 0..3 on the proven sequential path (drift not yet
  // established; R8 showed cold 2-refinement lam flips vertices).
  solve_seq();  // it = 0 (y = clip01(c) already)
#pragma unroll 1
  for (int it = 1; it <= 3; ++it) {
    update_y();
    solve_seq();
  }

#pragma unroll 2
  for (int it = 4; it <= N_PGD; ++it) {
    update_y();
    solve_pair();
  }

#pragma unroll
  for (int u = 0; u < 4; ++u) {
    *reinterpret_cast<float4*>(out + base + 4 * u) =
        make_float4(x[2 * u].x, x[2 * u].y, x[2 * u + 1].x, x[2 * u + 1].y);
  }
}

extern "C" void kernel_launch(void* const* d_in, const int* in_sizes, int n_in,
                              void* d_out, int out_size, void* d_ws, size_t ws_size,
                              hipStream_t stream) {
  const float* costs   = (const float*)d_in[0];
  const float* weights = (const float*)d_in[1];
  float* out           = (float*)d_out;

  const int n_rows  = in_sizes[0] / N_ITEMS;  // 16384
  const int threads = n_rows * 4;             // 4 lanes per row
  dim3 block(256);
  dim3 grid(threads / 256);
  pgd_knapsack<<<grid, block, 0, stream>>>(costs, weights, out);
}

// Round 15
// 112.750 us; speedup vs baseline: 1.0529x; 1.0529x over previous
//
#include <hip/hip_runtime.h>

// Problem constants (match reference)
#define N_ITEMS   64
#define CAPACITY  102.0f
#define N_PGD     120
#define ETA       0.1f

typedef float v2f __attribute__((ext_vector_type(2)));

// ---- DPP helpers: butterfly reductions over 4-lane quads ------------------
//   0xB1 = quad_perm [1,0,3,2] -> lane ^ 1
//   0x4E = quad_perm [2,3,0,1] -> lane ^ 2
// Both are quad-local, so a 4-lane problem-group never leaks into neighbors.
// All 4 lanes end bitwise-identical after the butterfly, so per-group
// decisions (bracket updates, lam) are uniform within the group.
template <int CTRL>
__device__ __forceinline__ float dpp_movf(float x) {
  return __builtin_bit_cast(
      float, __builtin_amdgcn_update_dpp(0, __builtin_bit_cast(int, x), CTRL,
                                         0xF, 0xF, true));
}

__device__ __forceinline__ float grp4_sum(float x) {
  x += dpp_movf<0xB1>(x);
  x += dpp_movf<0x4E>(x);
  return x;
}

__device__ __forceinline__ float grp4_max(float x) {
  x = fmaxf(x, dpp_movf<0xB1>(x));
  x = fmaxf(x, dpp_movf<0x4E>(x));
  return x;
}

__device__ __forceinline__ float clip01(float z) {
  return __builtin_amdgcn_fmed3f(z, 0.0f, 1.0f);  // single v_med3_f32
}

// False-position estimate from the bracket. Invariant: flo > 0 >= fhi
// (Illinois halving scales f-values by 0.5, preserving signs), so
// fhi - flo < 0 strictly -> no divide-by-zero/NaN; the med3 clamp at the
// call site absorbs any rounding excursion outside [lo, hi].
// Single rcp per pick: rcp is a quarter-rate trans op (R12's dual
// speculation added 3 rcps/iter and raised busy time; R14's paired probes
// degraded lam accuracy and refetched more code -- both reverted).
__device__ __forceinline__ float false_pos(float lo, float flo, float hi,
                                           float fhi) {
  const float t = fhi * __builtin_amdgcn_rcpf(fhi - flo);
  return fmaf(-t, hi - lo, hi);  // hi - fhi*(hi-lo)/(fhi-flo)
}

// 4 lanes per row, 16 items per lane. 16384 rows -> 65536 threads
// (1024 waves = 1 wave/SIMD). Measured optimum (R13) across the explored
// config space: 8-lane/2-waves and dual-row layouts cost more instructions
// than their utilization recovery (R7/R11); speculation/probe-pairing on the
// root-finder chain is net-neutral or worse (R12/R14).
__global__ __launch_bounds__(256, 1) void pgd_knapsack(
    const float* __restrict__ costs, const float* __restrict__ weights,
    float* __restrict__ out) {
  const int tid  = blockIdx.x * 256 + threadIdx.x;
  const int sub  = tid & 3;                 // lane within row-group
  const int base = (tid >> 2) * N_ITEMS + sub * 16;

  v2f w[8], ec[8], x[8], y[8];

  float B;     // bracket half-width: g(-B) = sum(w), g(+B) = 0 by construction
  float flo0;  // f(-B) = sum(w) - CAPACITY, exact, no eval needed
  {
    float cab = 0.0f;
#pragma unroll
    for (int u = 0; u < 4; ++u) {
      const float4 cq = *reinterpret_cast<const float4*>(costs + base + 4 * u);
      const float4 wq =
          *reinterpret_cast<const float4*>(weights + sub * 16 + 4 * u);
      w[2 * u]      = (v2f){wq.x, wq.y};
      w[2 * u + 1]  = (v2f){wq.z, wq.w};
      ec[2 * u]     = (v2f){ETA * cq.x, ETA * cq.y};
      ec[2 * u + 1] = (v2f){ETA * cq.z, ETA * cq.w};
      y[2 * u]      = (v2f){clip01(cq.x), clip01(cq.y)};
      y[2 * u + 1]  = (v2f){clip01(cq.z), clip01(cq.w)};
      cab = fmaxf(cab, fmaxf(fmaxf(fabsf(cq.x), fabsf(cq.y)),
                             fmaxf(fabsf(cq.z), fabsf(cq.w))));
    }
    cab = grp4_max(cab);
    // Every PGD iterate satisfies y_j in [-0.1 - eta*cab, 1 + eta*cab]
    // (since (1 - eta/||x||) * x_j in [-eta, 1]); with w_j >= 1 this makes
    // +-B a valid bracket: all coords clipped to 1 at -B, to 0 at +B.
    B = fmaf(ETA, cab, 1.1f) + 1e-3f;
    v2f sw = (w[0] + w[1]) + (w[2] + w[3]);
    sw = sw + ((w[4] + w[5]) + (w[6] + w[7]));
    flo0 = grp4_sum(sw.x + sw.y) - CAPACITY;  // = 340 - 102, exact
  }
  const float fhi0 = -CAPACITY;  // f(+B) = 0 - CAPACITY, exact

  float lam_est = 0.0f;  // unclamped root estimate, warm start across iters

  // g(lam) - CAPACITY over the 4-lane group (16 items/lane, 4 indep chains).
  auto eval_f = [&](float lam) -> float {
    const v2f nl = {-lam, -lam};
    v2f q[4];
#pragma unroll
    for (int p = 0; p < 4; ++p) {
      const v2f z0 = __builtin_elementwise_fma(nl, w[2 * p], y[2 * p]);
      const v2f z1 = __builtin_elementwise_fma(nl, w[2 * p + 1], y[2 * p + 1]);
      const v2f t0 = {clip01(z0.x), clip01(z0.y)};
      const v2f t1 = {clip01(z1.x), clip01(z1.y)};
      const v2f qq = w[2 * p] * t0;
      q[p] = __builtin_elementwise_fma(w[2 * p + 1], t1, qq);
    }
    const v2f qs = (q[0] + q[1]) + (q[2] + q[3]);
    return grp4_sum(qs.x + qs.y) - CAPACITY;
  };

  // ---- multiplier root-find on [-B, +B] + epilogue x = clip(y - lam*w) ----
  // R7/R10-proven solver: warm probe + 2 Illinois false positions + exact
  // final pick (3 evals = verified accuracy floor, R8; no data-dependent
  // freeze, R6; wave-uniform eval3 skip at bracket width <= 1e-5, R10).
  // Illinois halvings (0.5*flo / 0.5*fhi, selected by prevpos) are computed
  // BEFORE f lands -- off the critical path.
  auto solve_project = [&]() {
    float lo = -B, hi = B, flo = flo0, fhi = fhi0;
    bool prevpos;

    // eval 1: warm probe. lam_est is always inside [-B, B]: it is either 0
    // (first iteration) or a med3 clamp into a sub-bracket of [-B, B], and
    // B is a per-row constant -- so no clamp is needed here.
    float lam = lam_est;
    {
      const float f = eval_f(lam);
      const bool pos = f > 0.0f;
      flo = pos ? f : flo;
      lo  = pos ? lam : lo;
      fhi = pos ? fhi : f;
      hi  = pos ? hi : lam;
      prevpos = pos;
    }

    // eval 2: false position with Illinois halving (halved values selected
    // by prevpos, computed before f arrives)
    {
      lam = __builtin_amdgcn_fmed3f(false_pos(lo, flo, hi, fhi), lo, hi);
      const float fhi_a = prevpos ? 0.5f * fhi : fhi;  // off critical path
      const float flo_a = prevpos ? flo : 0.5f * flo;
      const float f = eval_f(lam);
      const bool pos = f > 0.0f;
      flo = pos ? f : flo_a;
      lo  = pos ? lam : lo;
      fhi = pos ? fhi_a : f;
      hi  = pos ? hi : lam;
      prevpos = pos;
    }

    // eval 3: identical Illinois step, skipped only if the whole wave's
    // brackets have already collapsed below 1e-5 (skip perturbs lam by
    // <= 1e-5, one-shot, non-accumulating).
    const bool tiny = (hi - lo) <= 1e-5f;
    if (!__all(tiny)) {
      lam = __builtin_amdgcn_fmed3f(false_pos(lo, flo, hi, fhi), lo, hi);
      const float fhi_a = prevpos ? 0.5f * fhi : fhi;
      const float flo_a = prevpos ? flo : 0.5f * flo;
      const float f = eval_f(lam);
      const bool pos = f > 0.0f;
      flo = pos ? f : flo_a;
      lo  = pos ? lam : lo;
      fhi = pos ? fhi_a : f;
      hi  = pos ? hi : lam;
    }

    // final derivative-free pick (no extra eval)
    const float pick =
        __builtin_amdgcn_fmed3f(false_pos(lo, flo, hi, fhi), lo, hi);
    lam_est = pick;
    const float lam_use = fmaxf(pick, 0.0f);  // inactive constraint -> 0

    const v2f nl = {-lam_use, -lam_use};
#pragma unroll
    for (int p = 0; p < 8; ++p) {
      const v2f z = __builtin_elementwise_fma(nl, w[p], y[p]);
      x[p] = (v2f){clip01(z.x), clip01(z.y)};
    }
  };

  // Iteration 0 peeled: y is already clip01(c).
  solve_project();

#pragma unroll 2
  for (int it = 1; it <= N_PGD; ++it) {
    // y = x + eta*(c - x/||x||) = (1 - eta/||x||)*x + eta*c
    v2f a = x[0] * x[0];
    a = __builtin_elementwise_fma(x[1], x[1], a);
    v2f b = x[2] * x[2];
    b = __builtin_elementwise_fma(x[3], x[3], b);
    v2f c2 = x[4] * x[4];
    c2 = __builtin_elementwise_fma(x[5], x[5], c2);
    v2f d = x[6] * x[6];
    d = __builtin_elementwise_fma(x[7], x[7], d);
    const v2f ab = (a + b) + (c2 + d);
    const float s2  = grp4_sum(ab.x + ab.y);
    const float inv = __builtin_amdgcn_rsqf(s2 + 1e-12f);
    const float s   = 1.0f - ETA * inv;
    const v2f sv = {s, s};
#pragma unroll
    for (int p = 0; p < 8; ++p)
      y[p] = __builtin_elementwise_fma(sv, x[p], ec[p]);

    solve_project();
  }

#pragma unroll
  for (int u = 0; u < 4; ++u) {
    *reinterpret_cast<float4*>(out + base + 4 * u) =
        make_float4(x[2 * u].x, x[2 * u].y, x[2 * u + 1].x, x[2 * u + 1].y);
  }
}

extern "C" void kernel_launch(void* const* d_in, const int* in_sizes, int n_in,
                              void* d_out, int out_size, void* d_ws, size_t ws_size,
                              hipStream_t stream) {
  const float* costs   = (const float*)d_in[0];
  const float* weights = (const float*)d_in[1];
  float* out           = (float*)d_out;

  const int n_rows  = in_sizes[0] / N_ITEMS;  // 16384
  const int threads = n_rows * 4;             // 4 lanes per row
  dim3 block(256);
  dim3 grid(threads / 256);
  pgd_knapsack<<<grid, block, 0, stream>>>(costs, weights, out);
}